// Round 9
// baseline (7584.926 us; speedup 1.0000x reference)
//
#include <hip/hip_runtime.h>
#include <hip/hip_bf16.h>

#define Bn 16
#define Tn 4096
#define IN_DIM 64
#define L 256
#define NL 10
#define PADROWS 512
#define TP (Tn + PADROWS)   // 4608
#define COLS 64

typedef __attribute__((ext_vector_type(8))) short short8;
typedef __attribute__((ext_vector_type(4))) float f32x4;
typedef unsigned short ushort_t;
typedef unsigned int uint_t;

__device__ inline ushort_t f2bf(float f) {
    uint_t u = __builtin_bit_cast(uint_t, f);
    u = u + 0x7fffu + ((u >> 16) & 1u);
    return (ushort_t)(u >> 16);
}
__device__ inline float bf2f(ushort_t v) {
    uint_t u = ((uint_t)v) << 16;
    return __builtin_bit_cast(float, u);
}

__device__ inline float fexp2f(float x) { return __builtin_amdgcn_exp2f(x); }
__device__ inline float frcpf(float x)  { return __builtin_amdgcn_rcpf(x); }
__device__ inline float tanh_fast(float x) {
    float e = fexp2f(x * 2.8853900817779268f);   // e^(2x)
    return 1.f - 2.f * frcpf(e + 1.f);
}
__device__ inline float sigm_fast(float x) {
    return frcpf(1.f + fexp2f(-1.4426950408889634f * x));
}

__device__ inline f32x4 mfma16(short8 a, short8 b, f32x4 c) {
    return __builtin_amdgcn_mfma_f32_16x16x32_bf16(a, b, c, 0, 0, 0);
}

__device__ inline void gld_lds16(const void* src, void* dst) {
    __builtin_amdgcn_global_load_lds(
        (const __attribute__((address_space(1))) void*)src,
        (__attribute__((address_space(3))) void*)dst, 16, 0, 0);
}

// bijective XCD-chunked swizzle for grid=1024 (1024 % 8 == 0, chunk=128)
__device__ inline int xcd_swz(int bid) {
    return (bid & 7) * 128 + (bid >> 3);
}

// ---------------------------------------------------------------------------
// prep: fp32 weights -> bf16, packed lane-linear per K-step:
//   [steps][16 rgrp][4 q][16 r][8 e]  (wave w, step t, fragment rt at
//   t*16384 + (2w+rt)*1024 + lane*16 -- fully coalesced 16B/lane)
// filt/gate concat-K: steps 0..7 = tap1 (unshifted h), 8..15 = tap0 (shifted).
// Also zero h pads.
// ---------------------------------------------------------------------------
__global__ void prep_kernel(
    const float* __restrict__ filt_w, const float* __restrict__ gate_w,
    const float* __restrict__ res_w,  const float* __restrict__ skip_w,
    const float* __restrict__ emb_w,  const float* __restrict__ fin1_w,
    const float* __restrict__ fin2_w, const float* __restrict__ out_w,
    ushort_t* __restrict__ Wfp, ushort_t* __restrict__ Wgp,
    ushort_t* __restrict__ Wrp, ushort_t* __restrict__ Wsp,
    ushort_t* __restrict__ Ws0, ushort_t* __restrict__ We,
    ushort_t* __restrict__ W1,  ushort_t* __restrict__ W2,
    ushort_t* __restrict__ Wo,
    ushort_t* __restrict__ h_a, ushort_t* __restrict__ h_b)
{
    const int stride = gridDim.x * blockDim.x;
    const int tid0 = blockIdx.x * blockDim.x + threadIdx.x;

    for (int idx = tid0; idx < NL * 16 * 1024 * 8; idx += stride) {
        int e  = idx & 7;
        int r  = (idx >> 3) & 15;
        int qq = (idx >> 7) & 3;
        int rg = (idx >> 9) & 15;
        int t  = (idx >> 13) & 15;
        int i  = idx >> 17;
        int row = rg * 16 + r;
        int k = t * 32 + qq * 8 + e;
        int tap = (k < 256) ? 1 : 0;
        int kk = k & 255;
        int src = ((i * 256 + row) * 256 + kk) * 2 + tap;
        Wfp[idx] = f2bf(filt_w[src]);
        Wgp[idx] = f2bf(gate_w[src]);
    }
    for (int idx = tid0; idx < NL * 8 * 1024 * 8; idx += stride) {
        int e  = idx & 7;
        int r  = (idx >> 3) & 15;
        int qq = (idx >> 7) & 3;
        int rg = (idx >> 9) & 15;
        int t  = (idx >> 13) & 7;
        int i  = idx >> 16;
        int row = rg * 16 + r;
        int k = t * 32 + qq * 8 + e;
        Wrp[idx] = f2bf(res_w[(i * 256 + row) * 256 + k]);
        Wsp[idx] = f2bf(skip_w[((i + 1) * 256 + row) * 256 + k]);
    }
    for (int idx = tid0; idx < L * L; idx += stride) {
        Ws0[idx] = f2bf(skip_w[idx]);
        W1[idx] = f2bf(fin1_w[idx]);
        W2[idx] = f2bf(fin2_w[idx]);
    }
    for (int idx = tid0; idx < L * IN_DIM; idx += stride) We[idx] = f2bf(emb_w[idx]);
    for (int idx = tid0; idx < 64 * L; idx += stride)     Wo[idx] = f2bf(out_w[idx]);
    for (int idx = tid0; idx < Bn * PADROWS * L; idx += stride) {
        int bb = idx >> 17;
        int r = idx & 131071;
        size_t off = (size_t)bb * TP * L + r;
        h_a[off] = 0;
        h_b[off] = 0;
    }
}

// ---------------------------------------------------------------------------
// embedding: h0 = relu(We @ x^T + eb); fin = Ws0 @ h0 + sb0 (first write)
// ---------------------------------------------------------------------------
__global__ __launch_bounds__(512, 4) void emb_kernel(
    const float* __restrict__ x,
    const ushort_t* __restrict__ We, const float* __restrict__ eb,
    const ushort_t* __restrict__ Ws0, const float* __restrict__ sb0,
    ushort_t* __restrict__ h_out, float* __restrict__ fin)
{
    __shared__ __align__(16) char gt[32 * 1024];

    const int tid = threadIdx.x;
    const int w = tid >> 6;
    const int ln = tid & 63;
    const int q = ln >> 4;
    const int n16 = ln & 15;
    const int lid = xcd_swz(blockIdx.x);
    const int b = lid >> 6;
    const int t0 = (lid & 63) * COLS;
    const int row0 = w * 32;

    f32x4 acc[2][4];
    #pragma unroll
    for (int rt = 0; rt < 2; ++rt)
        #pragma unroll
        for (int ct = 0; ct < 4; ++ct) acc[rt][ct] = (f32x4){0.f, 0.f, 0.f, 0.f};

    #pragma unroll
    for (int ks = 0; ks < 2; ++ks) {
        const int k = ks * 32 + q * 8;
        short8 bfr[4];
        #pragma unroll
        for (int ct = 0; ct < 4; ++ct) {
            int c = ct * 16 + n16;
            const float* xp = x + ((size_t)(b * Tn + t0 + c)) * IN_DIM + k;
            f32x4 x0 = *(const f32x4*)xp;
            f32x4 x1 = *(const f32x4*)(xp + 4);
            short8 v;
            v[0] = (short)f2bf(x0[0]); v[1] = (short)f2bf(x0[1]);
            v[2] = (short)f2bf(x0[2]); v[3] = (short)f2bf(x0[3]);
            v[4] = (short)f2bf(x1[0]); v[5] = (short)f2bf(x1[1]);
            v[6] = (short)f2bf(x1[2]); v[7] = (short)f2bf(x1[3]);
            bfr[ct] = v;
        }
        #pragma unroll
        for (int rt = 0; rt < 2; ++rt) {
            int row = row0 + rt * 16 + n16;
            short8 a = *(const short8*)(We + row * IN_DIM + k);
            #pragma unroll
            for (int ct = 0; ct < 4; ++ct)
                acc[rt][ct] = mfma16(a, bfr[ct], acc[rt][ct]);
        }
    }

    ushort_t* hob = h_out + ((size_t)(b * TP + PADROWS + t0)) * L;
    #pragma unroll
    for (int rt = 0; rt < 2; ++rt) {
        int i0 = row0 + rt * 16 + q * 4;
        f32x4 eb4 = *(const f32x4*)(eb + i0);
        #pragma unroll
        for (int ct = 0; ct < 4; ++ct) {
            int c = ct * 16 + n16;
            f32x4 h0 = acc[rt][ct] + eb4;
            float v0 = fmaxf(h0[0], 0.f), v1 = fmaxf(h0[1], 0.f);
            float v2 = fmaxf(h0[2], 0.f), v3 = fmaxf(h0[3], 0.f);
            uint_t lo = (uint_t)f2bf(v0) | ((uint_t)f2bf(v1) << 16);
            uint_t hi = (uint_t)f2bf(v2) | ((uint_t)f2bf(v3) << 16);
            *(uint2*)(hob + (size_t)c * L + i0) = make_uint2(lo, hi);
            int byt = c * 512 + ((i0 * 2) ^ ((c & 7) << 4));
            *(uint2*)(gt + byt) = make_uint2(lo, hi);
        }
    }
    __syncthreads();

    f32x4 accs[2][4];
    #pragma unroll
    for (int rt = 0; rt < 2; ++rt)
        #pragma unroll
        for (int ct = 0; ct < 4; ++ct) accs[rt][ct] = (f32x4){0.f, 0.f, 0.f, 0.f};

    for (int ks = 0; ks < 8; ++ks) {
        const int k = ks * 32 + q * 8;
        short8 bg[4];
        #pragma unroll
        for (int ct = 0; ct < 4; ++ct) {
            int c = ct * 16 + n16;
            bg[ct] = *(const short8*)(gt + c * 512 + ((k * 2) ^ ((c & 7) << 4)));
        }
        #pragma unroll
        for (int rt = 0; rt < 2; ++rt) {
            int row = row0 + rt * 16 + n16;
            short8 a = *(const short8*)(Ws0 + row * L + k);
            #pragma unroll
            for (int ct = 0; ct < 4; ++ct)
                accs[rt][ct] = mfma16(a, bg[ct], accs[rt][ct]);
        }
    }
    float* fob = fin + ((size_t)(b * Tn + t0)) * L;
    #pragma unroll
    for (int rt = 0; rt < 2; ++rt) {
        int i0 = row0 + rt * 16 + q * 4;
        f32x4 sb4 = *(const f32x4*)(sb0 + i0);
        #pragma unroll
        for (int ct = 0; ct < 4; ++ct) {
            int c = ct * 16 + n16;
            *(f32x4*)(fob + (size_t)c * L + i0) = accs[rt][ct] + sb4;
        }
    }
}

// ---------------------------------------------------------------------------
// one WaveNet layer, split-tap staging: LDS = 32 KiB -> 4 blocks/CU.
//   sm row c (512 B, 32 chunks of 16B; physical chunk p holds logical p^(c&7)):
//     stage1: h[t0+c-d]  -> pass A: filt/gate tap0 (packed steps 8..15)
//     stage2: h[t0+c]    -> pass B: filt/gate tap1 (steps 0..7) + res
//     then  : gated      -> skip GEMM
//     then  : hn         -> coalesced copy-out
//   fin += sk directly from registers (64B-sector-covered f32x4 RMW).
//   K-loops are barrier-free; weights stream L2->VGPR, 1-step reg prefetch.
// ---------------------------------------------------------------------------
__global__ __launch_bounds__(512, 8) void layer_kernel(
    const ushort_t* __restrict__ h_in, ushort_t* __restrict__ h_out,
    float* __restrict__ fin,
    const char* __restrict__ WfL, const char* __restrict__ WgL,
    const char* __restrict__ WrL, const char* __restrict__ WsL,
    const float* __restrict__ fb_, const float* __restrict__ gb_,
    const float* __restrict__ rb_, const float* __restrict__ sb_,
    int d)
{
    __shared__ __align__(16) char sm[32 * 1024];

    const int tid = threadIdx.x;
    const int w = tid >> 6;
    const int ln = tid & 63;
    const int q = ln >> 4;
    const int n16 = ln & 15;
    const int lid = xcd_swz(blockIdx.x);
    const int b = lid >> 6;
    const int t0 = (lid & 63) * COLS;
    const int row0 = w * 32;

    const ushort_t* hbase = h_in + ((size_t)(b * TP + PADROWS + t0)) * L;

    // ---- stage 1: SHIFTED rows h[t0+c-d] (tap0 operand)
    #pragma unroll
    for (int it = 0; it < 4; ++it) {
        int r0 = it * 16 + w * 2;            // wave-uniform even row
        int c  = r0 + (ln >> 5);             // per-lane row (r0 or r0+1)
        int chunk = (ln & 31) ^ (c & 7);     // pre-swizzled 16B chunk
        const ushort_t* src = hbase + ((long)c - d) * L + chunk * 8;
        gld_lds16(src, sm + r0 * 512);
    }
    __syncthreads();

    // ---- pass A: filt/gate over tap0 (packed steps 8..15), barrier-free
    f32x4 accf[2][4], accg[2][4];
    #pragma unroll
    for (int rt = 0; rt < 2; ++rt)
        #pragma unroll
        for (int ct = 0; ct < 4; ++ct) {
            accf[rt][ct] = (f32x4){0.f, 0.f, 0.f, 0.f};
            accg[rt][ct] = (f32x4){0.f, 0.f, 0.f, 0.f};
        }

    {
        const char* pf = WfL + 8 * 16384 + (w * 2) * 1024 + ln * 16;
        const char* pg = WgL + 8 * 16384 + (w * 2) * 1024 + ln * 16;
        short8 wf0 = *(const short8*)(pf);
        short8 wf1 = *(const short8*)(pf + 1024);
        short8 wg0 = *(const short8*)(pg);
        short8 wg1 = *(const short8*)(pg + 1024);
        for (int st = 0; st < 8; ++st) {
            const int nb = ((st < 7) ? st + 1 : 7) * 16384;
            short8 nf0 = *(const short8*)(pf + nb);
            short8 nf1 = *(const short8*)(pf + nb + 1024);
            short8 ng0 = *(const short8*)(pg + nb);
            short8 ng1 = *(const short8*)(pg + nb + 1024);
            const int kq2 = st * 64 + q * 16;
            #pragma unroll
            for (int ct = 0; ct < 4; ++ct) {
                int c = ct * 16 + n16;
                short8 bfr = *(const short8*)(sm + c * 512 + (kq2 ^ ((c & 7) << 4)));
                accf[0][ct] = mfma16(wf0, bfr, accf[0][ct]);
                accf[1][ct] = mfma16(wf1, bfr, accf[1][ct]);
                accg[0][ct] = mfma16(wg0, bfr, accg[0][ct]);
                accg[1][ct] = mfma16(wg1, bfr, accg[1][ct]);
            }
            wf0 = nf0; wf1 = nf1; wg0 = ng0; wg1 = ng1;
        }
    }
    __syncthreads();                         // pass A reads done

    // ---- stage 2: UNSHIFTED rows h[t0+c]
    #pragma unroll
    for (int it = 0; it < 4; ++it) {
        int r0 = it * 16 + w * 2;
        int c  = r0 + (ln >> 5);
        int chunk = (ln & 31) ^ (c & 7);
        const ushort_t* src = hbase + (long)c * L + chunk * 8;
        gld_lds16(src, sm + r0 * 512);
    }
    __syncthreads();

    // ---- pass B: filt/gate tap1 (steps 0..7) + res, shared B-frag
    f32x4 accr[2][4];
    #pragma unroll
    for (int rt = 0; rt < 2; ++rt)
        #pragma unroll
        for (int ct = 0; ct < 4; ++ct) accr[rt][ct] = (f32x4){0.f, 0.f, 0.f, 0.f};

    {
        const char* pf = WfL + (w * 2) * 1024 + ln * 16;
        const char* pg = WgL + (w * 2) * 1024 + ln * 16;
        const char* pr = WrL + (w * 2) * 1024 + ln * 16;
        short8 wf0 = *(const short8*)(pf);
        short8 wf1 = *(const short8*)(pf + 1024);
        short8 wg0 = *(const short8*)(pg);
        short8 wg1 = *(const short8*)(pg + 1024);
        short8 wr0 = *(const short8*)(pr);
        short8 wr1 = *(const short8*)(pr + 1024);
        for (int st = 0; st < 8; ++st) {
            const int nb = ((st < 7) ? st + 1 : 7) * 16384;
            short8 nf0 = *(const short8*)(pf + nb);
            short8 nf1 = *(const short8*)(pf + nb + 1024);
            short8 ng0 = *(const short8*)(pg + nb);
            short8 ng1 = *(const short8*)(pg + nb + 1024);
            short8 nr0 = *(const short8*)(pr + nb);
            short8 nr1 = *(const short8*)(pr + nb + 1024);
            const int kq2 = st * 64 + q * 16;
            #pragma unroll
            for (int ct = 0; ct < 4; ++ct) {
                int c = ct * 16 + n16;
                short8 bfr = *(const short8*)(sm + c * 512 + (kq2 ^ ((c & 7) << 4)));
                accf[0][ct] = mfma16(wf0, bfr, accf[0][ct]);
                accf[1][ct] = mfma16(wf1, bfr, accf[1][ct]);
                accg[0][ct] = mfma16(wg0, bfr, accg[0][ct]);
                accg[1][ct] = mfma16(wg1, bfr, accg[1][ct]);
                accr[0][ct] = mfma16(wr0, bfr, accr[0][ct]);
                accr[1][ct] = mfma16(wr1, bfr, accr[1][ct]);
            }
            wf0 = nf0; wf1 = nf1; wg0 = ng0; wg1 = ng1; wr0 = nr0; wr1 = nr1;
        }
    }
    __syncthreads();                         // pass B reads done

    // ---- activation: gated = tanh(f+fb)*sigmoid(g+gb) -> sm
    #pragma unroll
    for (int rt = 0; rt < 2; ++rt) {
        int i0 = row0 + rt * 16 + q * 4;
        f32x4 fb4 = *(const f32x4*)(fb_ + i0);
        f32x4 gb4 = *(const f32x4*)(gb_ + i0);
        #pragma unroll
        for (int ct = 0; ct < 4; ++ct) {
            int c = ct * 16 + n16;
            uint_t pk[2];
            #pragma unroll
            for (int h2 = 0; h2 < 2; ++h2) {
                float v0 = tanh_fast(accf[rt][ct][h2 * 2] + fb4[h2 * 2]) *
                           sigm_fast(accg[rt][ct][h2 * 2] + gb4[h2 * 2]);
                float v1 = tanh_fast(accf[rt][ct][h2 * 2 + 1] + fb4[h2 * 2 + 1]) *
                           sigm_fast(accg[rt][ct][h2 * 2 + 1] + gb4[h2 * 2 + 1]);
                pk[h2] = (uint_t)f2bf(v0) | ((uint_t)f2bf(v1) << 16);
            }
            int byt = c * 512 + ((i0 * 2) ^ ((c & 7) << 4));
            *(uint2*)(sm + byt) = make_uint2(pk[0], pk[1]);
        }
    }
    __syncthreads();

    // ---- skip GEMM over gated (Wsp steps 0..7)
    f32x4 accs[2][4];
    #pragma unroll
    for (int rt = 0; rt < 2; ++rt)
        #pragma unroll
        for (int ct = 0; ct < 4; ++ct) accs[rt][ct] = (f32x4){0.f, 0.f, 0.f, 0.f};

    {
        const char* ps = WsL + (w * 2) * 1024 + ln * 16;
        short8 ws0 = *(const short8*)(ps);
        short8 ws1 = *(const short8*)(ps + 1024);
        for (int st = 0; st < 8; ++st) {
            const int nb = ((st < 7) ? st + 1 : 7) * 16384;
            short8 ns0 = *(const short8*)(ps + nb);
            short8 ns1 = *(const short8*)(ps + nb + 1024);
            const int kq2 = st * 64 + q * 16;
            #pragma unroll
            for (int ct = 0; ct < 4; ++ct) {
                int c = ct * 16 + n16;
                short8 bg = *(const short8*)(sm + c * 512 + (kq2 ^ ((c & 7) << 4)));
                accs[0][ct] = mfma16(ws0, bg, accs[0][ct]);
                accs[1][ct] = mfma16(ws1, bg, accs[1][ct]);
            }
            ws0 = ns0; ws1 = ns1;
        }
    }
    __syncthreads();                         // skip-GEMM reads done

    // ---- epilogue: fin += sk (f32x4 RMW, 64B-covered); hn -> sm
    float* fob = fin + ((size_t)(b * Tn + t0)) * L;
    #pragma unroll
    for (int rt = 0; rt < 2; ++rt) {
        int i0 = row0 + rt * 16 + q * 4;
        f32x4 sb4 = *(const f32x4*)(sb_ + i0);
        f32x4 rb4 = *(const f32x4*)(rb_ + i0);
        #pragma unroll
        for (int ct = 0; ct < 4; ++ct) {
            int c = ct * 16 + n16;
            f32x4 sk = accs[rt][ct] + sb4;
            f32x4 hn = sk + accr[rt][ct] + rb4;
            f32x4* fp = (f32x4*)(fob + (size_t)c * L + i0);
            *fp = *fp + sk;
            uint_t hlo = (uint_t)f2bf(hn[0]) | ((uint_t)f2bf(hn[1]) << 16);
            uint_t hhi = (uint_t)f2bf(hn[2]) | ((uint_t)f2bf(hn[3]) << 16);
            int byt = c * 512 + ((i0 * 2) ^ ((c & 7) << 4));
            *(uint2*)(sm + byt) = make_uint2(hlo, hhi);
        }
    }
    __syncthreads();

    // ---- coalesced h copy-out: 512B contiguous per 32-lane half
    ushort_t* hob = h_out + ((size_t)(b * TP + PADROWS + t0)) * L;
    #pragma unroll
    for (int it = 0; it < 4; ++it) {
        int r0 = it * 16 + w * 2;
        int c  = r0 + (ln >> 5);
        short8 v = *(const short8*)(sm + c * 512 +
                                    (((ln & 31) * 16) ^ ((c & 7) << 4)));
        *(short8*)(hob + (size_t)c * L + (ln & 31) * 8) = v;
    }
}

// ---------------------------------------------------------------------------
// head: relu(fin)->fin1->relu->fin2->out_w->tanh
// ---------------------------------------------------------------------------
__global__ __launch_bounds__(512, 4) void final_kernel(
    const float* __restrict__ fin,
    const ushort_t* __restrict__ W1, const float* __restrict__ b1,
    const ushort_t* __restrict__ W2, const float* __restrict__ b2,
    const ushort_t* __restrict__ Wo, const float* __restrict__ ob,
    float* __restrict__ out)
{
    __shared__ __align__(16) char s1[32 * 1024];
    __shared__ __align__(16) char s2[32 * 1024];

    const int tid = threadIdx.x;
    const int w = tid >> 6;
    const int ln = tid & 63;
    const int q = ln >> 4;
    const int n16 = ln & 15;
    const int lid = xcd_swz(blockIdx.x);
    const int b = lid >> 6;
    const int t0 = (lid & 63) * COLS;
    const int row0 = w * 32;

    {
        int c = tid & 63;
        int kg = tid >> 6;
        const float* fp = fin + ((size_t)(b * Tn + t0 + c)) * L + kg * 32;
        #pragma unroll
        for (int j = 0; j < 8; ++j) {
            f32x4 v = *(const f32x4*)(fp + j * 4);
            uint_t lo = (uint_t)f2bf(fmaxf(v[0], 0.f)) | ((uint_t)f2bf(fmaxf(v[1], 0.f)) << 16);
            uint_t hi = (uint_t)f2bf(fmaxf(v[2], 0.f)) | ((uint_t)f2bf(fmaxf(v[3], 0.f)) << 16);
            int kk = kg * 32 + j * 4;
            *(uint2*)(s1 + c * 512 + ((kk * 2) ^ ((c & 7) << 4))) = make_uint2(lo, hi);
        }
    }
    __syncthreads();

    f32x4 acc[2][4];
    #pragma unroll
    for (int rt = 0; rt < 2; ++rt)
        #pragma unroll
        for (int ct = 0; ct < 4; ++ct) acc[rt][ct] = (f32x4){0.f, 0.f, 0.f, 0.f};
    for (int ks = 0; ks < 8; ++ks) {
        const int k = ks * 32 + q * 8;
        short8 bfr[4];
        #pragma unroll
        for (int ct = 0; ct < 4; ++ct) {
            int c = ct * 16 + n16;
            bfr[ct] = *(const short8*)(s1 + c * 512 + ((k * 2) ^ ((c & 7) << 4)));
        }
        #pragma unroll
        for (int rt = 0; rt < 2; ++rt) {
            int row = row0 + rt * 16 + n16;
            short8 a = *(const short8*)(W1 + row * L + k);
            #pragma unroll
            for (int ct = 0; ct < 4; ++ct) acc[rt][ct] = mfma16(a, bfr[ct], acc[rt][ct]);
        }
    }
    #pragma unroll
    for (int rt = 0; rt < 2; ++rt) {
        int i0 = row0 + rt * 16 + q * 4;
        f32x4 bb = *(const f32x4*)(b1 + i0);
        #pragma unroll
        for (int ct = 0; ct < 4; ++ct) {
            int c = ct * 16 + n16;
            f32x4 z = acc[rt][ct] + bb;
            uint_t lo = (uint_t)f2bf(fmaxf(z[0], 0.f)) | ((uint_t)f2bf(fmaxf(z[1], 0.f)) << 16);
            uint_t hi = (uint_t)f2bf(fmaxf(z[2], 0.f)) | ((uint_t)f2bf(fmaxf(z[3], 0.f)) << 16);
            *(uint2*)(s2 + c * 512 + ((i0 * 2) ^ ((c & 7) << 4))) = make_uint2(lo, hi);
        }
    }
    __syncthreads();

    #pragma unroll
    for (int rt = 0; rt < 2; ++rt)
        #pragma unroll
        for (int ct = 0; ct < 4; ++ct) acc[rt][ct] = (f32x4){0.f, 0.f, 0.f, 0.f};
    for (int ks = 0; ks < 8; ++ks) {
        const int k = ks * 32 + q * 8;
        short8 bfr[4];
        #pragma unroll
        for (int ct = 0; ct < 4; ++ct) {
            int c = ct * 16 + n16;
            bfr[ct] = *(const short8*)(s2 + c * 512 + ((k * 2) ^ ((c & 7) << 4)));
        }
        #pragma unroll
        for (int rt = 0; rt < 2; ++rt) {
            int row = row0 + rt * 16 + n16;
            short8 a = *(const short8*)(W2 + row * L + k);
            #pragma unroll
            for (int ct = 0; ct < 4; ++ct) acc[rt][ct] = mfma16(a, bfr[ct], acc[rt][ct]);
        }
    }
    #pragma unroll
    for (int rt = 0; rt < 2; ++rt) {
        int i0 = row0 + rt * 16 + q * 4;
        f32x4 bb = *(const f32x4*)(b2 + i0);
        #pragma unroll
        for (int ct = 0; ct < 4; ++ct) {
            int c = ct * 16 + n16;
            f32x4 z = acc[rt][ct] + bb;
            uint_t lo = (uint_t)f2bf(z[0]) | ((uint_t)f2bf(z[1]) << 16);
            uint_t hi = (uint_t)f2bf(z[2]) | ((uint_t)f2bf(z[3]) << 16);
            *(uint2*)(s1 + c * 512 + ((i0 * 2) ^ ((c & 7) << 4))) = make_uint2(lo, hi);
        }
    }
    __syncthreads();

    if (w < 4) {
        f32x4 acc3[4];
        #pragma unroll
        for (int ct = 0; ct < 4; ++ct) acc3[ct] = (f32x4){0.f, 0.f, 0.f, 0.f};
        for (int ks = 0; ks < 8; ++ks) {
            const int k = ks * 32 + q * 8;
            short8 bfr[4];
            #pragma unroll
            for (int ct = 0; ct < 4; ++ct) {
                int c = ct * 16 + n16;
                bfr[ct] = *(const short8*)(s1 + c * 512 + ((k * 2) ^ ((c & 7) << 4)));
            }
            short8 a = *(const short8*)(Wo + (w * 16 + n16) * L + k);
            #pragma unroll
            for (int ct = 0; ct < 4; ++ct) acc3[ct] = mfma16(a, bfr[ct], acc3[ct]);
        }
        int o0 = w * 16 + q * 4;
        f32x4 ob4 = *(const f32x4*)(ob + o0);
        float* obase = out + ((size_t)(b * Tn + t0)) * 64;
        #pragma unroll
        for (int ct = 0; ct < 4; ++ct) {
            int c = ct * 16 + n16;
            f32x4 v;
            #pragma unroll
            for (int j = 0; j < 4; ++j) v[j] = tanh_fast(acc3[ct][j] + ob4[j]);
            *(f32x4*)(obase + (size_t)c * 64 + o0) = v;
        }
    }
}

// ---------------------------------------------------------------------------
extern "C" void kernel_launch(void* const* d_in, const int* in_sizes, int n_in,
                              void* d_out, int out_size, void* d_ws, size_t ws_size,
                              hipStream_t stream)
{
    (void)in_sizes; (void)n_in; (void)out_size; (void)ws_size;
    const float* x      = (const float*)d_in[0];
    const float* emb_w  = (const float*)d_in[1];
    const float* emb_b  = (const float*)d_in[2];
    const float* filt_w = (const float*)d_in[3];
    const float* filt_b = (const float*)d_in[4];
    const float* gate_w = (const float*)d_in[5];
    const float* gate_b = (const float*)d_in[6];
    const float* res_w  = (const float*)d_in[7];
    const float* res_b  = (const float*)d_in[8];
    const float* skip_w = (const float*)d_in[9];
    const float* skip_b = (const float*)d_in[10];
    const float* fin1_w = (const float*)d_in[11];
    const float* fin1_b = (const float*)d_in[12];
    const float* fin2_w = (const float*)d_in[13];
    const float* fin2_b = (const float*)d_in[14];
    const float* out_w  = (const float*)d_in[15];
    const float* out_b  = (const float*)d_in[16];

    char* ws = (char*)d_ws;
    size_t off = 0;
    auto alloc = [&](size_t bytes) -> char* {
        char* p = ws + off;
        off += (bytes + 255) & ~(size_t)255;
        return p;
    };
    ushort_t* h_a = (ushort_t*)alloc((size_t)Bn * TP * L * 2);
    ushort_t* h_b = (ushort_t*)alloc((size_t)Bn * TP * L * 2);
    float*    fin = (float*)   alloc((size_t)Bn * Tn * L * 4);
    ushort_t* Wfp = (ushort_t*)alloc((size_t)NL * 16 * 1024 * 8 * 2);
    ushort_t* Wgp = (ushort_t*)alloc((size_t)NL * 16 * 1024 * 8 * 2);
    ushort_t* Wrp = (ushort_t*)alloc((size_t)NL * 8 * 1024 * 8 * 2);
    ushort_t* Wsp = (ushort_t*)alloc((size_t)NL * 8 * 1024 * 8 * 2);
    ushort_t* Ws0 = (ushort_t*)alloc((size_t)L * L * 2);
    ushort_t* We  = (ushort_t*)alloc((size_t)L * IN_DIM * 2);
    ushort_t* W1  = (ushort_t*)alloc((size_t)L * L * 2);
    ushort_t* W2  = (ushort_t*)alloc((size_t)L * L * 2);
    ushort_t* Wo  = (ushort_t*)alloc((size_t)64 * L * 2);

    prep_kernel<<<512, 256, 0, stream>>>(filt_w, gate_w, res_w, skip_w, emb_w,
        fin1_w, fin2_w, out_w, Wfp, Wgp, Wrp, Wsp, Ws0, We, W1, W2, Wo, h_a, h_b);

    emb_kernel<<<1024, 512, 0, stream>>>(x, We, emb_b, Ws0, skip_b, h_a, fin);

    ushort_t* hin = h_a;
    ushort_t* hout = h_b;
    for (int i = 0; i < NL; ++i) {
        layer_kernel<<<1024, 512, 0, stream>>>(hin, hout, fin,
            (const char*)Wfp + (size_t)i * 16 * 16384,
            (const char*)Wgp + (size_t)i * 16 * 16384,
            (const char*)Wrp + (size_t)i * 8 * 16384,
            (const char*)Wsp + (size_t)i * 8 * 16384,
            filt_b + i * L, gate_b + i * L, res_b + i * L, skip_b + (i + 1) * L,
            1 << i);
        ushort_t* t = hin; hin = hout; hout = t;
    }

    final_kernel<<<1024, 512, 0, stream>>>(fin, W1, fin1_b, W2, fin2_b,
        Wo, out_b, (float*)d_out);
}